// Round 6
// baseline (115.812 us; speedup 1.0000x reference)
//
#include <hip/hip_runtime.h>
#include <cstdint>
#include <cstddef>

// [B,H,N,Dh] = [4,16,2048,64]; out[b,h,m,d] = (sum_n softmax(QK^T)[n,m]) * v[b,h,m,d]
#define B_    4
#define H_    16
#define N_    2048
#define D_    64
#define BH_   (B_*H_)
#define SCALE 0.125f
#define QSCL  0.18033688011f      // SCALE * log2(e)

#define P2    128                 // fixed panel (rows in pass1 / cols in pass2) per wg
#define T2    128                 // streamed LDS tile rows
#define NT    (N_/T2)             // 16
#define NP2   (N_/P2)             // 16
#define TILEB 16384               // bytes per bf16 tile: 128 rows x 128 B
#define BHB   (NT*TILEB)          // 256 KB per (bh, tensor)

typedef __attribute__((ext_vector_type(8))) short bf16x8;
typedef __attribute__((ext_vector_type(4))) float f32x4;

#if __has_builtin(__builtin_amdgcn_exp2f)
#define EXP2(x) __builtin_amdgcn_exp2f(x)
#else
#define EXP2(x) exp2f(x)
#endif

__device__ __forceinline__ short f2bf(float f) {
    union { float f; unsigned u; } x; x.f = f;
    unsigned r = x.u + 0x7FFF + ((x.u >> 16) & 1);  // RNE
    return (short)(r >> 16);
}

// byte offset of chunk (row, cc) inside a (bh, tensor) panel; XOR-swizzled so
// 16-row-stride ds_read_b128 is bank-conflict-free (G4)
__device__ __forceinline__ size_t swz(int row, int cc) {
    return ((size_t)(row >> 7) * TILEB) + ((row & 127) << 7) + ((cc ^ (row & 7)) << 4);
}

// async global->LDS 16B copy (dest must be wave-uniform base + lane*16: our
// per-thread dest is base + t*16 = wavebase + lane*16 — linear, OK)
__device__ __forceinline__ void gload_lds16(const char* g, char* l) {
    __builtin_amdgcn_global_load_lds(
        (const __attribute__((address_space(1))) void*)g,
        (__attribute__((address_space(3))) void*)l, 16, 0, 0);
}

// ---------------------------------------------------------------------------
// Pre-pass: qk[] = [ Q' (bf16, x QSCL, swizzled image) | K' (bf16, swizzled) ]
// ---------------------------------------------------------------------------
__global__ __launch_bounds__(512)
void mha_convert(const float* __restrict__ q, const float* __restrict__ k,
                 char* __restrict__ qk)
{
    const int gid = blockIdx.x * 512 + threadIdx.x;     // 2*64*16384 chunks
    const int half = BH_ * N_ * 8;
    const bool isq = gid < half;
    const float* src = isq ? q : k;
    const float scl = isq ? QSCL : 1.0f;
    char* dst = qk + (isq ? 0 : (size_t)BH_ * BHB);
    const int id = isq ? gid : gid - half;
    const int bh  = id >> 14;            // 16384 chunks per bh
    const int row = (id >> 3) & 2047;
    const int cc  = id & 7;
    const float* p = src + ((size_t)bh * N_ + row) * D_ + cc * 8;
    float4 a = *(const float4*)p;
    float4 b = *(const float4*)(p + 4);
    bf16x8 o;
    o[0] = f2bf(a.x * scl); o[1] = f2bf(a.y * scl);
    o[2] = f2bf(a.z * scl); o[3] = f2bf(a.w * scl);
    o[4] = f2bf(b.x * scl); o[5] = f2bf(b.y * scl);
    o[6] = f2bf(b.z * scl); o[7] = f2bf(b.w * scl);
    *(bf16x8*)(dst + (size_t)bh * BHB + swz(row, cc)) = o;
}

// ---------------------------------------------------------------------------
// Pass 1: rinv[bh,n] = 1 / sum_m 2^(q'_n . k'_m)
// wg = (bh, 128-row panel); 8 waves x 16 rows; K' streamed, double-buffered
// via global_load_lds (2-phase pipeline).
// ---------------------------------------------------------------------------
__global__ __launch_bounds__(512)
void mha_rowsum3(const char* __restrict__ qk, float* __restrict__ rinv)
{
    __shared__ __align__(16) char KT[2][TILEB];

    const int t = threadIdx.x, w = t >> 6, l = t & 63;
    const int wid = (blockIdx.x & 7) * 128 + (blockIdx.x >> 3);  // XCD swizzle (1024%8==0)
    const int bh = wid >> 4, rb = wid & 15;

    const char* Qp = qk + (size_t)bh * BHB;
    const char* Kp = qk + (size_t)BH_ * BHB + (size_t)bh * BHB;

    // Fixed A frags: row rb*128 + w*16 + (l&15); chunks kh*4+(l>>4)
    bf16x8 af[2];
    #pragma unroll
    for (int kh = 0; kh < 2; ++kh)
        af[kh] = *(const bf16x8*)(Qp + swz(rb * P2 + w * 16 + (l & 15), kh * 4 + (l >> 4)));

    float rs[4] = {0.f, 0.f, 0.f, 0.f};

    auto compute = [&](const char* kt) {
        #pragma unroll
        for (int cj = 0; cj < 8; ++cj) {
            const int krow = cj * 16 + (l & 15);
            const int kb = (krow & 127) << 7;
            bf16x8 b0 = *(const bf16x8*)(kt + kb + (((l >> 4) ^ (krow & 7)) << 4));
            bf16x8 b1 = *(const bf16x8*)(kt + kb + (((4 + (l >> 4)) ^ (krow & 7)) << 4));
            f32x4 c = {0.f, 0.f, 0.f, 0.f};
            c = __builtin_amdgcn_mfma_f32_16x16x32_bf16(af[0], b0, c, 0, 0, 0);
            c = __builtin_amdgcn_mfma_f32_16x16x32_bf16(af[1], b1, c, 0, 0, 0);
            rs[0] += EXP2(c[0]);
            rs[1] += EXP2(c[1]);
            rs[2] += EXP2(c[2]);
            rs[3] += EXP2(c[3]);
        }
    };

    // prologue: stage tile 0
    gload_lds16(Kp + t * 16,        KT[0] + t * 16);
    gload_lds16(Kp + 8192 + t * 16, KT[0] + 8192 + t * 16);
    __syncthreads();

    #pragma unroll 1
    for (int ct = 0; ct < NT - 1; ++ct) {
        const char* src = Kp + (size_t)(ct + 1) * TILEB;
        char* dst = KT[(ct + 1) & 1];
        gload_lds16(src + t * 16,        dst + t * 16);
        gload_lds16(src + 8192 + t * 16, dst + 8192 + t * 16);
        compute(KT[ct & 1]);
        __syncthreads();       // drains this iter's stage loads (they had compute to land)
    }
    compute(KT[(NT - 1) & 1]);

    // Reduce across the 16 col-lanes (l&15); D-row = (l>>4)*4 + reg.
    #pragma unroll
    for (int i = 0; i < 4; ++i) {
        rs[i] += __shfl_xor(rs[i], 1);
        rs[i] += __shfl_xor(rs[i], 2);
        rs[i] += __shfl_xor(rs[i], 4);
        rs[i] += __shfl_xor(rs[i], 8);
    }
    if ((l & 15) == 0) {
        const int rbase = rb * P2 + w * 16 + (l >> 4) * 4;
        #pragma unroll
        for (int i = 0; i < 4; ++i)
            rinv[(size_t)bh * N_ + rbase + i] = 1.0f / rs[i];
    }
}

// ---------------------------------------------------------------------------
// Pass 2: colsum[m] = sum_n 2^(q'_n . k'_m) * rinv[n]; out = colsum[m]*v[m,:]
// wg = (bh, 128-col panel); Q' streamed, double-buffered; rv double-buffered.
// ---------------------------------------------------------------------------
__global__ __launch_bounds__(512)
void mha_colsum3(const char* __restrict__ qk, const float* __restrict__ rinv,
                 const float* __restrict__ v, float* __restrict__ out)
{
    __shared__ __align__(16) char QT[2][TILEB];
    __shared__ float rv[2][T2];
    __shared__ float cs[P2];

    const int t = threadIdx.x, w = t >> 6, l = t & 63;
    const int wid = (blockIdx.x & 7) * 128 + (blockIdx.x >> 3);
    const int bh = wid >> 4, cb = wid & 15;

    const char* Qp = qk + (size_t)bh * BHB;
    const char* Kp = qk + (size_t)BH_ * BHB + (size_t)bh * BHB;
    const float* Rg = rinv + (size_t)bh * N_;

    // Fixed B frags: col cb*128 + w*16 + (l&15)
    bf16x8 kf[2];
    #pragma unroll
    for (int kh = 0; kh < 2; ++kh)
        kf[kh] = *(const bf16x8*)(Kp + swz(cb * P2 + w * 16 + (l & 15), kh * 4 + (l >> 4)));

    float ca = 0.f;

    auto compute = [&](const char* qt, const float* rvb) {
        #pragma unroll
        for (int rj = 0; rj < 8; ++rj) {
            const int qr = rj * 16 + (l & 15);
            const int qb = (qr & 127) << 7;
            bf16x8 a0 = *(const bf16x8*)(qt + qb + (((l >> 4) ^ (qr & 7)) << 4));
            bf16x8 a1 = *(const bf16x8*)(qt + qb + (((4 + (l >> 4)) ^ (qr & 7)) << 4));
            float4 r4 = *(const float4*)&rvb[rj * 16 + (l >> 4) * 4];
            f32x4 c = {0.f, 0.f, 0.f, 0.f};
            c = __builtin_amdgcn_mfma_f32_16x16x32_bf16(a0, kf[0], c, 0, 0, 0);
            c = __builtin_amdgcn_mfma_f32_16x16x32_bf16(a1, kf[1], c, 0, 0, 0);
            ca += EXP2(c[0]) * r4.x + EXP2(c[1]) * r4.y
                + EXP2(c[2]) * r4.z + EXP2(c[3]) * r4.w;
        }
    };

    // prologue: stage tile 0 + rv 0
    gload_lds16(Qp + t * 16,        QT[0] + t * 16);
    gload_lds16(Qp + 8192 + t * 16, QT[0] + 8192 + t * 16);
    if (t < T2) rv[0][t] = Rg[t];
    __syncthreads();

    #pragma unroll 1
    for (int rt = 0; rt < NT - 1; ++rt) {
        const int nxt = (rt + 1) & 1;
        const char* src = Qp + (size_t)(rt + 1) * TILEB;
        char* dst = QT[nxt];
        gload_lds16(src + t * 16,        dst + t * 16);
        gload_lds16(src + 8192 + t * 16, dst + 8192 + t * 16);
        if (t < T2) rv[nxt][t] = Rg[(rt + 1) * T2 + t];
        compute(QT[rt & 1], rv[rt & 1]);
        __syncthreads();
    }
    compute(QT[(NT - 1) & 1], rv[(NT - 1) & 1]);

    // Butterfly across the 4 row-groups -> lanes 0..15 hold colsum of col w*16+l
    ca += __shfl_xor(ca, 16);
    ca += __shfl_xor(ca, 32);
    if (l < 16) cs[w * 16 + l] = ca;
    __syncthreads();

    // out[m][d] = colsum[m] * v[m][d]  (128 rows x 64 d, float4-vectorized)
    const float4* Vg = (const float4*)(v + ((size_t)bh * N_ + cb * P2) * D_);
    float4* Og = (float4*)(out + ((size_t)bh * N_ + cb * P2) * D_);
    #pragma unroll
    for (int i = 0; i < 4; ++i) {
        int id = i * 512 + t;                // 2048 float4 units
        float s = cs[id >> 4];
        float4 vv = Vg[id];
        float4 o; o.x = vv.x * s; o.y = vv.y * s; o.z = vv.z * s; o.w = vv.w * s;
        Og[id] = o;
    }
}

// ===========================================================================
// Fallback (R2 path) if ws_size is too small for the bf16 staging buffers.
// ===========================================================================
#define FTS 128
#define FNT 16

__device__ __forceinline__ bf16x8 cvt8(const float* p) {
    float4 a = *(const float4*)p;
    float4 b = *(const float4*)(p + 4);
    bf16x8 r;
    r[0] = f2bf(a.x); r[1] = f2bf(a.y); r[2] = f2bf(a.z); r[3] = f2bf(a.w);
    r[4] = f2bf(b.x); r[5] = f2bf(b.y); r[6] = f2bf(b.z); r[7] = f2bf(b.w);
    return r;
}
__device__ __forceinline__ void fstage(char* lds, const float* src, int t) {
    #pragma unroll
    for (int i = 0; i < 2; ++i) {
        int ch = i * 512 + t, r = ch >> 3, cc = ch & 7;
        bf16x8 v = cvt8(src + (size_t)r * D_ + cc * 8);
        *(bf16x8*)(lds + r * 128 + ((cc ^ (r & 7)) << 4)) = v;
    }
}
__device__ __forceinline__ bf16x8 fread(const char* lds, int row, int cc) {
    return *(const bf16x8*)(lds + row * 128 + ((cc ^ (row & 7)) << 4));
}

__global__ __launch_bounds__(512)
void mha_rowsum_fb(const float* __restrict__ q, const float* __restrict__ k,
                   float* __restrict__ rinv)
{
    __shared__ __align__(16) char KT[FTS * 128];
    const int t = threadIdx.x, w = t >> 6, l = t & 63;
    const int bh = blockIdx.x / FNT, rb = blockIdx.x % FNT;
    const float* Qg = q + (size_t)bh * N_ * D_;
    const float* Kg = k + (size_t)bh * N_ * D_;
    const int qrow = rb * FTS + w * 16 + (l & 15);
    bf16x8 af[2];
    #pragma unroll
    for (int kh = 0; kh < 2; ++kh)
        af[kh] = cvt8(Qg + (size_t)qrow * D_ + kh * 32 + (l >> 4) * 8);
    float rs[4] = {0.f, 0.f, 0.f, 0.f};
    for (int ct = 0; ct < FNT; ++ct) {
        __syncthreads();
        fstage(KT, Kg + (size_t)ct * FTS * D_, t);
        __syncthreads();
        #pragma unroll
        for (int cj = 0; cj < 8; ++cj) {
            const int krow = cj * 16 + (l & 15);
            f32x4 c = {0.f, 0.f, 0.f, 0.f};
            #pragma unroll
            for (int kh = 0; kh < 2; ++kh)
                c = __builtin_amdgcn_mfma_f32_16x16x32_bf16(af[kh], fread(KT, krow, kh * 4 + (l >> 4)), c, 0, 0, 0);
            rs[0] += __expf(c[0] * SCALE); rs[1] += __expf(c[1] * SCALE);
            rs[2] += __expf(c[2] * SCALE); rs[3] += __expf(c[3] * SCALE);
        }
    }
    #pragma unroll
    for (int i = 0; i < 4; ++i) {
        rs[i] += __shfl_xor(rs[i], 1); rs[i] += __shfl_xor(rs[i], 2);
        rs[i] += __shfl_xor(rs[i], 4); rs[i] += __shfl_xor(rs[i], 8);
    }
    if ((l & 15) == 0) {
        const int rbase = rb * FTS + w * 16 + (l >> 4) * 4;
        #pragma unroll
        for (int i = 0; i < 4; ++i)
            rinv[(size_t)bh * N_ + rbase + i] = 1.0f / rs[i];
    }
}

__global__ __launch_bounds__(512)
void mha_colsum_fb(const float* __restrict__ q, const float* __restrict__ k,
                   const float* __restrict__ v, const float* __restrict__ rinv,
                   float* __restrict__ out)
{
    __shared__ __align__(16) char QT[FTS * 128];
    __shared__ float rv[FTS];
    __shared__ float cs[FTS];
    const int t = threadIdx.x, w = t >> 6, l = t & 63;
    const int bh = blockIdx.x / FNT, cb = blockIdx.x % FNT;
    const float* Qg = q + (size_t)bh * N_ * D_;
    const float* Kg = k + (size_t)bh * N_ * D_;
    const float* Rg = rinv + (size_t)bh * N_;
    const int kcol = cb * FTS + w * 16 + (l & 15);
    bf16x8 kf[2];
    #pragma unroll
    for (int kh = 0; kh < 2; ++kh)
        kf[kh] = cvt8(Kg + (size_t)kcol * D_ + kh * 32 + (l >> 4) * 8);
    float ca = 0.f;
    for (int rt = 0; rt < FNT; ++rt) {
        __syncthreads();
        fstage(QT, Qg + (size_t)rt * FTS * D_, t);
        if (t < FTS) rv[t] = Rg[rt * FTS + t];
        __syncthreads();
        #pragma unroll
        for (int rj = 0; rj < 8; ++rj) {
            const int qr = rj * 16 + (l & 15);
            f32x4 c = {0.f, 0.f, 0.f, 0.f};
            #pragma unroll
            for (int kh = 0; kh < 2; ++kh)
                c = __builtin_amdgcn_mfma_f32_16x16x32_bf16(fread(QT, qr, kh * 4 + (l >> 4)), kf[kh], c, 0, 0, 0);
            float4 r4 = *(const float4*)&rv[rj * 16 + (l >> 4) * 4];
            ca += __expf(c[0] * SCALE) * r4.x + __expf(c[1] * SCALE) * r4.y
                + __expf(c[2] * SCALE) * r4.z + __expf(c[3] * SCALE) * r4.w;
        }
    }
    ca += __shfl_xor(ca, 16); ca += __shfl_xor(ca, 32);
    if (l < 16) cs[w * 16 + l] = ca;
    __syncthreads();
    const float4* Vg = (const float4*)(v + (size_t)bh * N_ * D_ + (size_t)cb * FTS * D_);
    float4* Og = (float4*)(out + (size_t)bh * N_ * D_ + (size_t)cb * FTS * D_);
    #pragma unroll
    for (int i = 0; i < 4; ++i) {
        int id = i * 512 + t;
        float s = cs[id >> 4];
        float4 vv = Vg[id];
        float4 o; o.x = vv.x * s; o.y = vv.y * s; o.z = vv.z * s; o.w = vv.w * s;
        Og[id] = o;
    }
}

// ---------------------------------------------------------------------------
extern "C" void kernel_launch(void* const* d_in, const int* in_sizes, int n_in,
                              void* d_out, int out_size, void* d_ws, size_t ws_size,
                              hipStream_t stream)
{
    const float* q = (const float*)d_in[0];
    const float* k = (const float*)d_in[1];
    const float* v = (const float*)d_in[2];
    float* out = (float*)d_out;

    const size_t qkBytes = (size_t)2 * BH_ * BHB;          // 32 MB
    const size_t need = qkBytes + (size_t)BH_ * N_ * 4;    // + rinv 512 KB

    if (ws_size >= need) {
        char* qk = (char*)d_ws;
        float* rinv = (float*)(qk + qkBytes);
        mha_convert<<<dim3(2 * BH_ * N_ * 8 / 512), dim3(512), 0, stream>>>(q, k, qk);
        mha_rowsum3<<<dim3(BH_ * NP2), dim3(512), 0, stream>>>(qk, rinv);
        mha_colsum3<<<dim3(BH_ * NP2), dim3(512), 0, stream>>>(qk, rinv, v, out);
    } else {
        float* rinv = (float*)d_ws;
        mha_rowsum_fb<<<dim3(BH_ * FNT), dim3(512), 0, stream>>>(q, k, rinv);
        mha_colsum_fb<<<dim3(BH_ * FNT), dim3(512), 0, stream>>>(q, k, v, rinv, out);
    }
}